// Round 1
// baseline (255.612 us; speedup 1.0000x reference)
//
#include <hip/hip_runtime.h>

#define ALPHA 0.2f
static constexpr int NN = 50000;          // nodes
static constexpr int DEG = 32;
static constexpr long NE = (long)NN * DEG; // 1.6M edges
static constexpr int FD = 64;             // out feature dim

// workspace layout (float offsets)
static constexpr long WS_HN1 = 0;
static constexpr long WS_HN2 = WS_HN1 + NN;
static constexpr long WS_HE1 = WS_HN2 + NN;
static constexpr long WS_HV  = WS_HE1 + NN;          // NN*64
static constexpr long WS_EV  = WS_HV + (long)NN*FD;  // NN*64
static constexpr long WS_ST  = WS_EV + (long)NN*FD;  // 4*NN: [sqn][sn][sqe][se]
static constexpr long WS_P   = WS_ST + 4L*NN;        // 250*4 partials

// ---------------- kernel 1: h_v = node_fts(50000x256) @ W_node(256x64) ----------------
__global__ __launch_bounds__(256) void k_hv(const float* __restrict__ A,
                                            const float* __restrict__ W,
                                            float* __restrict__ hv) {
    __shared__ float As[16][65];   // [k][m], padded
    __shared__ float Ws[16][64];   // [k][n]
    const int t  = threadIdx.x;
    const int m0 = blockIdx.x * 64;
    const int tr = t >> 4, tc = t & 15;      // 16x16 thread grid, 4x4 micro-tile
    const int lr = t >> 2, seg = t & 3;      // A-load: row lr, float4 at seg*4
    const int wk = t >> 4, wc = t & 15;      // W-load: k-row wk, float4 at wc*4

    float acc[4][4] = {};
    for (int k0 = 0; k0 < 256; k0 += 16) {
        int row = m0 + lr;
        float4 av = make_float4(0.f, 0.f, 0.f, 0.f);
        if (row < NN)
            av = *reinterpret_cast<const float4*>(&A[(long)row * 256 + k0 + seg * 4]);
        As[seg*4+0][lr] = av.x; As[seg*4+1][lr] = av.y;
        As[seg*4+2][lr] = av.z; As[seg*4+3][lr] = av.w;
        *reinterpret_cast<float4*>(&Ws[wk][wc*4]) =
            *reinterpret_cast<const float4*>(&W[(k0 + wk) * 64 + wc * 4]);
        __syncthreads();
        #pragma unroll
        for (int kk = 0; kk < 16; ++kk) {
            float a0 = As[kk][tr*4+0], a1 = As[kk][tr*4+1];
            float a2 = As[kk][tr*4+2], a3 = As[kk][tr*4+3];
            float b0 = Ws[kk][tc*4+0], b1 = Ws[kk][tc*4+1];
            float b2 = Ws[kk][tc*4+2], b3 = Ws[kk][tc*4+3];
            acc[0][0] += a0*b0; acc[0][1] += a0*b1; acc[0][2] += a0*b2; acc[0][3] += a0*b3;
            acc[1][0] += a1*b0; acc[1][1] += a1*b1; acc[1][2] += a1*b2; acc[1][3] += a1*b3;
            acc[2][0] += a2*b0; acc[2][1] += a2*b1; acc[2][2] += a2*b2; acc[2][3] += a2*b3;
            acc[3][0] += a3*b0; acc[3][1] += a3*b1; acc[3][2] += a3*b2; acc[3][3] += a3*b3;
        }
        __syncthreads();
    }
    #pragma unroll
    for (int q = 0; q < 4; ++q) {
        int row = m0 + tr * 4 + q;
        if (row < NN) {
            float4 v = make_float4(acc[q][0], acc[q][1], acc[q][2], acc[q][3]);
            *reinterpret_cast<float4*>(&hv[(long)row * 64 + tc * 4]) = v;
        }
    }
}

// ---------------- kernel 1b: per-node scalars h.a_n1, h.a_n2, h.a_e1 ----------------
__global__ __launch_bounds__(256) void k_scal(const float* __restrict__ hv,
                                              const float* __restrict__ a_node,
                                              const float* __restrict__ a_edge,
                                              float* __restrict__ ws) {
    const int lane = threadIdx.x & 63, w = threadIdx.x >> 6;
    const int r = blockIdx.x * 4 + w;
    float h  = hv[(long)r * 64 + lane];
    float s1 = h * a_node[lane];
    float s2 = h * a_node[64 + lane];
    float s3 = h * a_edge[lane];
    #pragma unroll
    for (int m = 32; m >= 1; m >>= 1) {
        s1 += __shfl_xor(s1, m);
        s2 += __shfl_xor(s2, m);
        s3 += __shfl_xor(s3, m);
    }
    if (lane == 0) {
        ws[WS_HN1 + r] = s1;
        ws[WS_HN2 + r] = s2;
        ws[WS_HE1 + r] = s3;
    }
}

// ---------------- kernel 2: e_v rows 0..49999 = edge_fts(r,0:32) @ W_edge(32x64) -----
__global__ __launch_bounds__(256) void k_ev(const float* __restrict__ ef,
                                            const float* __restrict__ We,
                                            float* __restrict__ ev) {
    const int lane = threadIdx.x & 63, w = threadIdx.x >> 6;
    const int r = blockIdx.x * 4 + w;
    float acc = 0.f;
    #pragma unroll
    for (int k = 0; k < 32; ++k)
        acc += ef[(long)r * 32 + k] * We[k * 64 + lane];
    ev[(long)r * 64 + lane] = acc;
}

// ---------------- kernel 3: main per-node attention + gather-accumulate -------------
__global__ __launch_bounds__(256) void k_edge(const float* __restrict__ ef,
                                              const int*   __restrict__ edges,
                                              const float* __restrict__ a_edge,
                                              const float* __restrict__ hn1,
                                              const float* __restrict__ hn2,
                                              const float* __restrict__ he1,
                                              const float* __restrict__ hv,
                                              const float* __restrict__ ev,
                                              float* __restrict__ st,
                                              float* __restrict__ out) {
    __shared__ float efl[128 * 33];   // 128 edges x 32 feats, pad 33 -> conflict-free
    const int t = threadIdx.x;
    const long base = (long)blockIdx.x * 128 * 32;
    #pragma unroll
    for (int q = 0; q < 16; ++q) {
        int el = q * 256 + t;                 // 0..4095, coalesced global read
        efl[(el >> 5) * 33 + (el & 31)] = ef[base + el];
    }
    __syncthreads();

    const int w = t >> 6, lane = t & 63, i = lane & 31;
    const int n = blockIdx.x * 4 + w;
    const long e = (long)n * 32 + i;
    const int d = edges[e * 2 + 1];

    // node attention logit
    float attn = hn1[n] + hn2[d];
    attn = attn >= 0.f ? attn : ALPHA * attn;
    float wn = __expf(fminf(fmaxf(attn, -2.f), 2.f));

    // edge attention logit
    float atte = he1[n];
    const int rbase = (w * 32 + i) * 33;
    #pragma unroll
    for (int k = 0; k < 32; ++k)
        atte += efl[rbase + k] * a_edge[64 + k];
    atte = atte >= 0.f ? atte : ALPHA * atte;
    float we = __expf(fminf(fmaxf(atte, -2.f), 2.f));

    // 32-wide segment softmax (both 32-lane halves hold identical copies)
    float dn = wn, de = we;
    #pragma unroll
    for (int m = 16; m >= 1; m >>= 1) { dn += __shfl_xor(dn, m); de += __shfl_xor(de, m); }
    float nn = wn / dn, ne = we / de;

    // variance partials (per node)
    float sqn = nn * nn, sqe = ne * ne, sn = nn, se = ne;
    #pragma unroll
    for (int m = 16; m >= 1; m >>= 1) {
        sqn += __shfl_xor(sqn, m); sn += __shfl_xor(sn, m);
        sqe += __shfl_xor(sqe, m); se += __shfl_xor(se, m);
    }
    if (lane == 0) {
        st[n]           = sqn;
        st[NN + n]      = sn;
        st[2L*NN + n]   = sqe;
        st[3L*NN + n]   = se;
    }

    // gather-accumulate: out rows are 64-wide, lane j = feature j
    float accn = 0.f, acce = 0.f;
    #pragma unroll 8
    for (int ii = 0; ii < 32; ++ii) {
        int   di  = __shfl(d, ii);
        float nni = __shfl(nn, ii);
        float nei = __shfl(ne, ii);
        accn += nni * hv[(long)di * 64 + lane];
        acce += nei * ev[(long)di * 64 + lane];
    }
    out[(long)n * 64 + lane]                  = accn;
    out[(long)NN * 64 + (long)n * 64 + lane]  = acce;
}

// ---------------- kernel 4a: deterministic stats reduction, stage 1 -----------------
__global__ __launch_bounds__(256) void k_red1(const float* __restrict__ st,
                                              float* __restrict__ part) {
    const int t = threadIdx.x, b = blockIdx.x;
    float v[4] = {0.f, 0.f, 0.f, 0.f};
    int n = b * 200 + t;
    if (t < 200) {
        v[0] = st[n];
        v[1] = st[NN + n];
        v[2] = st[2L*NN + n];
        v[3] = st[3L*NN + n];
    }
    #pragma unroll
    for (int m = 32; m >= 1; m >>= 1)
        for (int c = 0; c < 4; ++c) v[c] += __shfl_xor(v[c], m);
    __shared__ float ls[4][4];
    const int w = t >> 6, lane = t & 63;
    if (lane == 0)
        for (int c = 0; c < 4; ++c) ls[w][c] = v[c];
    __syncthreads();
    if (t == 0)
        for (int c = 0; c < 4; ++c)
            part[(long)b * 4 + c] = ls[0][c] + ls[1][c] + ls[2][c] + ls[3][c];
}

// ---------------- kernel 4b: final variance (single wave, double accum) -------------
__global__ __launch_bounds__(64) void k_red2(const float* __restrict__ part,
                                             float* __restrict__ out) {
    const int t = threadIdx.x;
    double v[4] = {0, 0, 0, 0};
    for (int b = t; b < 250; b += 64)
        for (int c = 0; c < 4; ++c) v[c] += (double)part[(long)b * 4 + c];
    #pragma unroll
    for (int m = 32; m >= 1; m >>= 1)
        for (int c = 0; c < 4; ++c) v[c] += __shfl_xor(v[c], m);
    if (t == 0) {
        const double M = (double)NE;
        double varn = (v[0] - v[1] * v[1] / M) / (M - 1.0);
        double vare = (v[2] - v[3] * v[3] / M) / (M - 1.0);
        out[6400000] = (float)varn;
        out[6400001] = (float)vare;
    }
}

extern "C" void kernel_launch(void* const* d_in, const int* in_sizes, int n_in,
                              void* d_out, int out_size, void* d_ws, size_t ws_size,
                              hipStream_t stream) {
    const float* node_fts = (const float*)d_in[0];
    const float* edge_fts = (const float*)d_in[1];
    const int*   edges    = (const int*)  d_in[2];
    const float* W_node   = (const float*)d_in[3];
    const float* W_edge   = (const float*)d_in[4];
    const float* a_node   = (const float*)d_in[5];
    const float* a_edge   = (const float*)d_in[6];
    float* out = (float*)d_out;
    float* ws  = (float*)d_ws;

    float* hv  = ws + WS_HV;
    float* ev  = ws + WS_EV;
    float* st  = ws + WS_ST;
    float* prt = ws + WS_P;

    k_hv  <<<(NN + 63) / 64, 256, 0, stream>>>(node_fts, W_node, hv);
    k_scal<<<NN / 4,        256, 0, stream>>>(hv, a_node, a_edge, ws);
    k_ev  <<<NN / 4,        256, 0, stream>>>(edge_fts, W_edge, ev);
    k_edge<<<NN / 4,        256, 0, stream>>>(edge_fts, edges, a_edge,
                                              ws + WS_HN1, ws + WS_HN2, ws + WS_HE1,
                                              hv, ev, st, out);
    k_red1<<<250, 256, 0, stream>>>(st, prt);
    k_red2<<<1,    64, 0, stream>>>(prt, out);
}

// Round 2
// 166.420 us; speedup vs baseline: 1.5359x; 1.5359x over previous
//
#include <hip/hip_runtime.h>
#include <hip/hip_fp16.h>

#define ALPHA 0.2f
static constexpr int NN = 50000;
static constexpr long NE = (long)NN * 32;

// workspace layout (float offsets)
static constexpr long WS_HN1 = 0;
static constexpr long WS_HN2 = NN;
static constexpr long WS_HE1 = 2L * NN;
static constexpr long WS_ST  = 3L * NN;        // 2*NN: [sum nn^2][sum ne^2]
static constexpr long WS_P   = 5L * NN;        // 512 floats of partials
static constexpr long WS_HEV = 5L * NN + 512;  // __half[NN*128], 16B-aligned

// ---- kernel 1: h_v GEMM (50000x256 @ 256x64) + f16 pack + attention dots ----
__global__ __launch_bounds__(256) void k_hv(const float* __restrict__ A,
                                            const float* __restrict__ W,
                                            const float* __restrict__ a_node,
                                            const float* __restrict__ a_edge,
                                            __half* __restrict__ hev,
                                            float* __restrict__ hn1,
                                            float* __restrict__ hn2,
                                            float* __restrict__ he1) {
    __shared__ float As[16][65];
    __shared__ float Ws[16][64];
    const int t  = threadIdx.x;
    const int m0 = blockIdx.x * 64;
    const int tr = t >> 4, tc = t & 15;
    const int lr = t >> 2, seg = t & 3;
    const int wk = t >> 4, wc = t & 15;

    float acc[4][4] = {};
    for (int k0 = 0; k0 < 256; k0 += 16) {
        int row = m0 + lr;
        float4 av = make_float4(0.f, 0.f, 0.f, 0.f);
        if (row < NN)
            av = *reinterpret_cast<const float4*>(&A[(long)row * 256 + k0 + seg * 4]);
        As[seg*4+0][lr] = av.x; As[seg*4+1][lr] = av.y;
        As[seg*4+2][lr] = av.z; As[seg*4+3][lr] = av.w;
        *reinterpret_cast<float4*>(&Ws[wk][wc*4]) =
            *reinterpret_cast<const float4*>(&W[(k0 + wk) * 64 + wc * 4]);
        __syncthreads();
        #pragma unroll
        for (int kk = 0; kk < 16; ++kk) {
            float a0 = As[kk][tr*4+0], a1 = As[kk][tr*4+1];
            float a2 = As[kk][tr*4+2], a3 = As[kk][tr*4+3];
            float b0 = Ws[kk][tc*4+0], b1 = Ws[kk][tc*4+1];
            float b2 = Ws[kk][tc*4+2], b3 = Ws[kk][tc*4+3];
            acc[0][0] += a0*b0; acc[0][1] += a0*b1; acc[0][2] += a0*b2; acc[0][3] += a0*b3;
            acc[1][0] += a1*b0; acc[1][1] += a1*b1; acc[1][2] += a1*b2; acc[1][3] += a1*b3;
            acc[2][0] += a2*b0; acc[2][1] += a2*b1; acc[2][2] += a2*b2; acc[2][3] += a2*b3;
            acc[3][0] += a3*b0; acc[3][1] += a3*b1; acc[3][2] += a3*b2; acc[3][3] += a3*b3;
        }
        __syncthreads();
    }

    // per-thread slices of the attention vectors (feature tc*4+j)
    float an1[4], an2[4], ae1[4];
    #pragma unroll
    for (int j = 0; j < 4; ++j) {
        an1[j] = a_node[tc*4 + j];
        an2[j] = a_node[64 + tc*4 + j];
        ae1[j] = a_edge[tc*4 + j];
    }

    #pragma unroll
    for (int q = 0; q < 4; ++q) {
        float p1 = 0.f, p2 = 0.f, p3 = 0.f;
        #pragma unroll
        for (int j = 0; j < 4; ++j) {
            p1 += acc[q][j] * an1[j];
            p2 += acc[q][j] * an2[j];
            p3 += acc[q][j] * ae1[j];
        }
        #pragma unroll
        for (int m = 1; m <= 8; m <<= 1) {   // reduce across the 16 tc lanes
            p1 += __shfl_xor(p1, m);
            p2 += __shfl_xor(p2, m);
            p3 += __shfl_xor(p3, m);
        }
        int row = m0 + tr * 4 + q;
        if (row < NN) {
            ushort4 hp;
            hp.x = __half_as_ushort(__float2half(acc[q][0]));
            hp.y = __half_as_ushort(__float2half(acc[q][1]));
            hp.z = __half_as_ushort(__float2half(acc[q][2]));
            hp.w = __half_as_ushort(__float2half(acc[q][3]));
            *reinterpret_cast<ushort4*>(&hev[(long)row * 128 + tc * 4]) = hp;
            if (tc == 0) { hn1[row] = p1; hn2[row] = p2; he1[row] = p3; }
        }
    }
}

// ---- kernel 2: e_v rows 0..49999 -> f16 second half of hev ----
__global__ __launch_bounds__(256) void k_ev(const float* __restrict__ ef,
                                            const float* __restrict__ We,
                                            __half* __restrict__ hev) {
    const int lane = threadIdx.x & 63, w = threadIdx.x >> 6;
    const int r = blockIdx.x * 4 + w;
    float acc = 0.f;
    #pragma unroll
    for (int k = 0; k < 32; ++k)
        acc += ef[(long)r * 32 + k] * We[k * 64 + lane];
    hev[(long)r * 128 + 64 + lane] = __float2half(acc);
}

// ---- kernel 3: per-node attention + f16 gather-accumulate ----
__global__ __launch_bounds__(256) void k_edge(const float* __restrict__ ef,
                                              const int*   __restrict__ edges,
                                              const float* __restrict__ a_edge,
                                              const float* __restrict__ hn1,
                                              const float* __restrict__ hn2,
                                              const float* __restrict__ he1,
                                              const __half* __restrict__ hev,
                                              float* __restrict__ st,
                                              float* __restrict__ out) {
    const int t = threadIdx.x;
    const int w = t >> 6, l = t & 63;
    const int n = blockIdx.x * 4 + w;
    const int i = l >> 1, h = l & 1;          // lane pair (2i,2i+1) owns edge i
    const long ebase = (long)n * 32;

    // edge-feature dot: each lane does 16 of the 32 features
    const float* efb = ef + (ebase + i) * 32 + h * 16;
    float dot = 0.f;
    #pragma unroll
    for (int j = 0; j < 4; ++j) {
        float4 v = *reinterpret_cast<const float4*>(efb + j * 4);
        float4 a = *reinterpret_cast<const float4*>(&a_edge[64 + h * 16 + j * 4]);
        dot += v.x*a.x + v.y*a.y + v.z*a.z + v.w*a.w;
    }
    dot += __shfl_xor(dot, 1);                // full 32-feature dot in both lanes

    const int d = edges[(ebase + i) * 2 + 1];

    float attn = hn1[n] + hn2[d];
    attn = attn >= 0.f ? attn : ALPHA * attn;
    float wn = __expf(fminf(fmaxf(attn, -2.f), 2.f));

    float atte = he1[n] + dot;
    atte = atte >= 0.f ? atte : ALPHA * atte;
    float we = __expf(fminf(fmaxf(atte, -2.f), 2.f));

    // segment softmax: parity reduce (masks 2..32) sums each edge exactly once
    float dn = wn, de = we;
    #pragma unroll
    for (int m = 2; m <= 32; m <<= 1) { dn += __shfl_xor(dn, m); de += __shfl_xor(de, m); }
    float nn = wn / dn, ne = we / de;

    // variance partials: only sum of squares needed (sum of weights == 1 analytically)
    float sqn = nn * nn, sqe = ne * ne;
    #pragma unroll
    for (int m = 2; m <= 32; m <<= 1) { sqn += __shfl_xor(sqn, m); sqe += __shfl_xor(sqe, m); }
    if (l == 0) { st[n] = sqn; st[NN + n] = sqe; }

    // gather: lanes 0..31 accumulate node_out feats (2l,2l+1); 32..63 edge_out
    const bool isE = l >= 32;
    float a0 = 0.f, a1 = 0.f;
    #pragma unroll
    for (int ii = 0; ii < 32; ++ii) {
        int   di  = __builtin_amdgcn_readlane(d, 2 * ii);
        float wni = __int_as_float(__builtin_amdgcn_readlane(__float_as_int(nn), 2 * ii));
        float wei = __int_as_float(__builtin_amdgcn_readlane(__float_as_int(ne), 2 * ii));
        float wt  = isE ? wei : wni;
        __half2 hv2 = *reinterpret_cast<const __half2*>(&hev[(long)di * 128 + l * 2]);
        float2 f = __half22float2(hv2);
        a0 = fmaf(wt, f.x, a0);
        a1 = fmaf(wt, f.y, a1);
    }
    long off = isE ? ((long)NN * 64 + (long)n * 64 + (l - 32) * 2)
                   : ((long)n * 64 + l * 2);
    *reinterpret_cast<float2*>(&out[off]) = make_float2(a0, a1);
}

// ---- kernel 4a: stats reduction stage 1 ----
__global__ __launch_bounds__(256) void k_red1(const float* __restrict__ st,
                                              float* __restrict__ part) {
    const int t = threadIdx.x;
    const int n = blockIdx.x * 256 + t;
    float v0 = 0.f, v1 = 0.f;
    if (n < NN) { v0 = st[n]; v1 = st[NN + n]; }
    #pragma unroll
    for (int m = 1; m <= 32; m <<= 1) { v0 += __shfl_xor(v0, m); v1 += __shfl_xor(v1, m); }
    __shared__ float ls[4][2];
    const int wv = t >> 6;
    if ((t & 63) == 0) { ls[wv][0] = v0; ls[wv][1] = v1; }
    __syncthreads();
    if (t == 0) {
        part[(long)blockIdx.x * 2]     = ls[0][0] + ls[1][0] + ls[2][0] + ls[3][0];
        part[(long)blockIdx.x * 2 + 1] = ls[0][1] + ls[1][1] + ls[2][1] + ls[3][1];
    }
}

// ---- kernel 4b: final variances ----
__global__ __launch_bounds__(64) void k_red2(const float* __restrict__ part,
                                             float* __restrict__ out) {
    const int t = threadIdx.x;
    double v0 = 0.0, v1 = 0.0;
    for (int b = t; b < 196; b += 64) {
        v0 += (double)part[b * 2];
        v1 += (double)part[b * 2 + 1];
    }
    #pragma unroll
    for (int m = 1; m <= 32; m <<= 1) { v0 += __shfl_xor(v0, m); v1 += __shfl_xor(v1, m); }
    if (t == 0) {
        const double M = (double)NE;
        const double corr = (double)NN * (double)NN / M;   // (sum w)^2 / M, sum w == NN
        out[6400000] = (float)((v0 - corr) / (M - 1.0));
        out[6400001] = (float)((v1 - corr) / (M - 1.0));
    }
}

extern "C" void kernel_launch(void* const* d_in, const int* in_sizes, int n_in,
                              void* d_out, int out_size, void* d_ws, size_t ws_size,
                              hipStream_t stream) {
    const float* node_fts = (const float*)d_in[0];
    const float* edge_fts = (const float*)d_in[1];
    const int*   edges    = (const int*)  d_in[2];
    const float* W_node   = (const float*)d_in[3];
    const float* W_edge   = (const float*)d_in[4];
    const float* a_node   = (const float*)d_in[5];
    const float* a_edge   = (const float*)d_in[6];
    float* out = (float*)d_out;
    float* ws  = (float*)d_ws;

    float*  hn1 = ws + WS_HN1;
    float*  hn2 = ws + WS_HN2;
    float*  he1 = ws + WS_HE1;
    float*  st  = ws + WS_ST;
    float*  prt = ws + WS_P;
    __half* hev = (__half*)(ws + WS_HEV);

    k_hv  <<<(NN + 63) / 64, 256, 0, stream>>>(node_fts, W_node, a_node, a_edge,
                                               hev, hn1, hn2, he1);
    k_ev  <<<NN / 4, 256, 0, stream>>>(edge_fts, W_edge, hev);
    k_edge<<<NN / 4, 256, 0, stream>>>(edge_fts, edges, a_edge, hn1, hn2, he1,
                                       hev, st, out);
    k_red1<<<196, 256, 0, stream>>>(st, prt);
    k_red2<<<1, 64, 0, stream>>>(prt, out);
}